// Round 1
// baseline (3497.826 us; speedup 1.0000x reference)
//
#include <hip/hip_runtime.h>
#include <hip/hip_bf16.h>
#include <math.h>

#define E_DIM 1024
#define FF_DIM 4096
#define LAYERS 24
#define MPAD 272      // 17 * 16 (tokens padded)
#define SPAD 288      // vT / P column padding (9 * 32)
#define KCP 608       // conv K (588) padded to 19*32

typedef __attribute__((ext_vector_type(8))) short short8;
typedef __attribute__((ext_vector_type(8))) __bf16 bf16x8;
typedef __attribute__((ext_vector_type(4))) float float4_t;
typedef __attribute__((ext_vector_type(4))) unsigned short ushort4_t;

union ABu { short8 s; bf16x8 b; };

__device__ __forceinline__ float4_t MFMA(short8 a, short8 b, float4_t c) {
  ABu ua, ub; ua.s = a; ub.s = b;
  return __builtin_amdgcn_mfma_f32_16x16x32_bf16(ua.b, ub.b, c, 0, 0, 0);
}

__device__ __forceinline__ unsigned short f2bf(float f) {
  union { float f; unsigned int u; } v; v.f = f;
  unsigned int u = v.u;
  u += 0x7fffu + ((u >> 16) & 1u);   // round-to-nearest-even
  return (unsigned short)(u >> 16);
}

// ---------------------------------------------------------------------------
// prep: im2col of frame -> Pm[256][608] bf16 ; conv_w -> Wp[1024][608] bf16
// ---------------------------------------------------------------------------
__global__ void prep_kernel(const float* __restrict__ frame, const float* __restrict__ conv_w,
                            unsigned short* __restrict__ Pm, unsigned short* __restrict__ Wp) {
  int b = blockIdx.x, tid = threadIdx.x;
  if (b < 256) {
    int pr = b >> 4, pc = b & 15;
    for (int kk = tid; kk < KCP; kk += 256) {
      unsigned short us = 0;
      if (kk < 588) {
        int c = kk / 196, rem = kk % 196;
        int i = rem / 14, j = rem % 14;
        us = f2bf(frame[c * 224 * 224 + (pr * 14 + i) * 224 + (pc * 14 + j)]);
      }
      Pm[b * KCP + kk] = us;
    }
  } else {
    int n = b - 256;
    for (int kk = tid; kk < KCP; kk += 256) {
      unsigned short us = (kk < 588) ? f2bf(conv_w[n * 588 + kk]) : (unsigned short)0;
      Wp[n * KCP + kk] = us;
    }
  }
}

// ---------------------------------------------------------------------------
// pb_cls: overlap matrix Mi[32][256], pb[256], x[0] = cls_emb, zero pads
// ---------------------------------------------------------------------------
__global__ void pb_cls_kernel(const float* __restrict__ bboxes, const float* __restrict__ cls_emb,
                              float* __restrict__ pb, float* __restrict__ Mi, float* __restrict__ x,
                              unsigned short* __restrict__ h, unsigned short* __restrict__ vTb) {
  __shared__ float sb[128];
  __shared__ float red[256];
  int tid = threadIdx.x;
  if (tid < 128) sb[tid] = bboxes[tid];
  __syncthreads();
  int p = tid;
  float px1 = (float)((p & 15) * 14), py1 = (float)((p >> 4) * 14);
  float px2 = px1 + 14.f, py2 = py1 + 14.f;
  float s = 0.f;
  for (int r = 0; r < 32; ++r) {
    float bx1 = sb[r * 4 + 0], by1 = sb[r * 4 + 1], bx2 = sb[r * 4 + 2], by2 = sb[r * 4 + 3];
    float iw = fmaxf(fminf(bx2, px2) - fmaxf(bx1, px1), 0.f);
    float ih = fmaxf(fminf(by2, py2) - fmaxf(by1, py1), 0.f);
    float ov = iw * ih * (1.f / 196.f);
    Mi[r * 256 + p] = ov;
    s += ov;
  }
  red[tid] = s;
  __syncthreads();
  for (int off = 128; off > 0; off >>= 1) {
    if (tid < off) red[tid] = fmaxf(red[tid], red[tid + off]);
    __syncthreads();
  }
  pb[p] = s / (red[0] + 1e-6f);
  for (int j = 0; j < 4; ++j) x[tid * 4 + j] = cls_emb[tid * 4 + j];
  // zero h pad rows [257..272) so padded-GEMM garbage stays finite & deterministic
  for (int i = tid; i < 15 * 1024; i += 256) h[257 * 1024 + i] = 0;
  // zero vT pad cols [272..288)
  for (int i = tid; i < 16 * 64 * 16; i += 256) {
    int dr = i >> 4;
    vTb[(size_t)dr * SPAD + 272 + (i & 15)] = 0;
  }
}

// ---------------------------------------------------------------------------
// conv GEMM: x[1+m][n] = relu(Pm[m][:] . Wp[n][:]) ; grid 64 (n-tiles of 16)
// ---------------------------------------------------------------------------
__global__ __launch_bounds__(256) void conv_gemm(const unsigned short* __restrict__ Pm,
                                                 const unsigned short* __restrict__ Wp,
                                                 float* __restrict__ x) {
  int n0 = blockIdx.x * 16;
  int tid = threadIdx.x, wave = tid >> 6, lane = tid & 63;
  int lg = lane >> 4, lc = lane & 15;
  float4_t acc[4] = {{0,0,0,0},{0,0,0,0},{0,0,0,0},{0,0,0,0}};
  const unsigned short* bp = Wp + (size_t)(n0 + lc) * KCP + lg * 8;
  const unsigned short* apt[4];
#pragma unroll
  for (int t = 0; t < 4; ++t) apt[t] = Pm + (size_t)((wave + t * 4) * 16 + lc) * KCP + lg * 8;
  for (int s = 0; s < 19; ++s) {
    short8 bf = *(const short8*)bp; bp += 32;
#pragma unroll
    for (int t = 0; t < 4; ++t) {
      short8 af = *(const short8*)apt[t]; apt[t] += 32;
      acc[t] = MFMA(af, bf, acc[t]);
    }
  }
#pragma unroll
  for (int t = 0; t < 4; ++t) {
    int mbase = (wave + t * 4) * 16 + lg * 4;
#pragma unroll
    for (int r = 0; r < 4; ++r) {
      float v = fmaxf(acc[t][r], 0.f);
      x[(size_t)(1 + mbase + r) * E_DIM + n0 + lc] = v;
    }
  }
}

// ---------------------------------------------------------------------------
// Swapped-operand GEMM: C[m][n] = A[m][:] (bf16) . W[:][n] (fp32->bf16)
// grid = NT*KS*2 blocks; XCD-paired decode; each block: 16 cols, M-half, K-chunk
// EPI 0: q/k/vT scatter (+bias)  EPI 1: quickgelu -> m_buf (+bias)  EPI 2: fp32 partial
// ---------------------------------------------------------------------------
template <int EPI>
__global__ __launch_bounds__(256) void gemm_nk(
    const unsigned short* __restrict__ A, int lda,
    const float* __restrict__ Wa, const float* __restrict__ Wb, const float* __restrict__ Wc,
    const float* __restrict__ ba, const float* __restrict__ bb, const float* __restrict__ bc,
    int Ntot, int k_len, int NT,
    unsigned short* __restrict__ oq, unsigned short* __restrict__ okk,
    unsigned short* __restrict__ ovT, unsigned short* __restrict__ om,
    float* __restrict__ opart) {
  int b = blockIdx.x;
  int p = ((b >> 4) << 3) | (b & 7);   // pair id: b and b+8 share weight slice & XCD
  int half = (b >> 3) & 1;
  int nt = p % NT, ks = p / NT;

  int tid = threadIdx.x, wave = tid >> 6, lane = tid & 63;
  int lg = lane >> 4, lc = lane & 15;

  const float* W; const float* bias; int ncol;
  if (EPI == 0) {
    int sel = nt >> 6; ncol = (nt & 63) << 4;
    W = (sel == 0) ? Wa : ((sel == 1) ? Wb : Wc);
    bias = (sel == 0) ? ba : ((sel == 1) ? bb : bc);
  } else {
    ncol = nt << 4; W = Wa; bias = ba;
  }

  int mt_lo = half ? 9 : 0;
  int mt_hi = half ? 17 : 9;
  int mt[3]; int nmt = 0;
#pragma unroll
  for (int t = 0; t < 3; ++t) {
    int mm = mt_lo + wave + t * 4;
    mt[t] = (mm < mt_hi) ? mm : mt_lo;
    if (mm < mt_hi) nmt = t + 1;
  }

  int kb0 = ks * k_len;
  const float* wp = W + (size_t)(kb0 + lg * 8) * Ntot + ncol + lc;
  const unsigned short* ap0 = A + (size_t)(mt[0] * 16 + lc) * lda + kb0 + lg * 8;
  const unsigned short* ap1 = A + (size_t)(mt[1] * 16 + lc) * lda + kb0 + lg * 8;
  const unsigned short* ap2 = A + (size_t)(mt[2] * 16 + lc) * lda + kb0 + lg * 8;

  float4_t acc0 = {0,0,0,0}, acc1 = {0,0,0,0}, acc2 = {0,0,0,0};
  int nsteps = k_len >> 5;
  size_t wstep = (size_t)32 * Ntot;

#pragma unroll 2
  for (int s = 0; s < nsteps; ++s) {
    float wv[8];
#pragma unroll
    for (int i = 0; i < 8; ++i) wv[i] = wp[(size_t)i * Ntot];
    wp += wstep;
    short8 wf;
#pragma unroll
    for (int i = 0; i < 8; ++i) wf[i] = (short)f2bf(wv[i]);
    short8 a0 = *(const short8*)ap0; ap0 += 32;
    acc0 = MFMA(wf, a0, acc0);
    if (nmt > 1) { short8 a1 = *(const short8*)ap1; acc1 = MFMA(wf, a1, acc1); }
    ap1 += 32;
    if (nmt > 2) { short8 a2 = *(const short8*)ap2; acc2 = MFMA(wf, a2, acc2); }
    ap2 += 32;
  }

  float4_t bvv = {0,0,0,0};
  if (bias) bvv = *(const float4_t*)(bias + ncol + lg * 4);
  float4_t accs[3] = {acc0, acc1, acc2};

  if (EPI == 0) {
    int sel = nt >> 6;
    int head = ncol >> 6;
    int dbase = (ncol & 63) + lg * 4;
#pragma unroll
    for (int t = 0; t < 3; ++t) {
      if (t < nmt) {
        int m = mt[t] * 16 + lc;
        if (sel < 2) {
          unsigned short* dst = (sel == 0 ? oq : okk) + ((size_t)(head * MPAD + m)) * 64 + dbase;
          ushort4_t hv;
#pragma unroll
          for (int r = 0; r < 4; ++r) hv[r] = f2bf(accs[t][r] + bvv[r]);
          *(ushort4_t*)dst = hv;
        } else {
#pragma unroll
          for (int r = 0; r < 4; ++r)
            ovT[(size_t)(head * 64 + dbase + r) * SPAD + m] = f2bf(accs[t][r] + bvv[r]);
        }
      }
    }
  } else if (EPI == 1) {
#pragma unroll
    for (int t = 0; t < 3; ++t) {
      if (t < nmt) {
        int m = mt[t] * 16 + lc;
        ushort4_t hv;
#pragma unroll
        for (int r = 0; r < 4; ++r) {
          float v = accs[t][r] + bvv[r];
          v = v / (1.f + __expf(-1.702f * v));   // quick_gelu
          hv[r] = f2bf(v);
        }
        *(ushort4_t*)(om + (size_t)m * FF_DIM + ncol + lg * 4) = hv;
      }
    }
  } else {
#pragma unroll
    for (int t = 0; t < 3; ++t) {
      if (t < nmt) {
        int m = mt[t] * 16 + lc;
        float4_t v = accs[t];
        *(float4_t*)(opart + ((size_t)ks * MPAD + m) * E_DIM + ncol + lg * 4) = v;
      }
    }
  }
}

// ---------------------------------------------------------------------------
// Attention: grid = 16 heads * 17 q-tiles; full softmax (max/sum via shfl+LDS)
// ---------------------------------------------------------------------------
__global__ __launch_bounds__(256) void attn_kernel(
    const unsigned short* __restrict__ qb, const unsigned short* __restrict__ kb,
    const unsigned short* __restrict__ vT, const float* __restrict__ pb,
    unsigned short* __restrict__ ob) {
  int head = blockIdx.x / 17, qt = blockIdx.x % 17;
  int q0 = qt * 16;
  int tid = threadIdx.x, wave = tid >> 6, lane = tid & 63;
  int lg = lane >> 4, lc = lane & 15;
  const unsigned short* qh = qb + (size_t)head * MPAD * 64;
  const unsigned short* kh = kb + (size_t)head * MPAD * 64;
  const unsigned short* vh = vT + (size_t)head * 64 * SPAD;

  short8 aq0 = *(const short8*)(qh + (size_t)(q0 + lc) * 64 + lg * 8);
  short8 aq1 = *(const short8*)(qh + (size_t)(q0 + lc) * 64 + 32 + lg * 8);

  float4_t sc[5];
  int st[5]; int nst = 0;
#pragma unroll
  for (int j = 0; j < 5; ++j) {
    int t = wave + j * 4;
    st[j] = (t < 17) ? t : 0;
    if (t < 17) nst = j + 1;
    sc[j] = (float4_t){0,0,0,0};
  }
#pragma unroll
  for (int j = 0; j < 5; ++j) {
    if (j < nst) {
      const unsigned short* kp = kh + (size_t)(st[j] * 16 + lc) * 64 + lg * 8;
      short8 b0 = *(const short8*)kp;
      short8 b1 = *(const short8*)(kp + 32);
      sc[j] = MFMA(aq0, b0, sc[j]);
      sc[j] = MFMA(aq1, b1, sc[j]);
    }
  }
  // scale + mask + cls-row bias; running max
  float mx[4] = {-1e30f, -1e30f, -1e30f, -1e30f};
#pragma unroll
  for (int j = 0; j < 5; ++j) {
    if (j < nst) {
      int sg = st[j] * 16 + lc;
#pragma unroll
      for (int r = 0; r < 4; ++r) {
        float v = sc[j][r] * 0.125f;
        if (sg >= 257) v = -1e30f;
        else if (q0 + lg * 4 + r == 0 && sg >= 1) v += pb[sg - 1];
        sc[j][r] = v;
        mx[r] = fmaxf(mx[r], v);
      }
    }
  }
#pragma unroll
  for (int r = 0; r < 4; ++r) {
    mx[r] = fmaxf(mx[r], __shfl_xor(mx[r], 1, 64));
    mx[r] = fmaxf(mx[r], __shfl_xor(mx[r], 2, 64));
    mx[r] = fmaxf(mx[r], __shfl_xor(mx[r], 4, 64));
    mx[r] = fmaxf(mx[r], __shfl_xor(mx[r], 8, 64));
  }
  __shared__ float smax[4][16];
  __shared__ float sden[4][16];
  __shared__ __align__(16) unsigned short P[16][SPAD];
  if (lc == 0) {
#pragma unroll
    for (int r = 0; r < 4; ++r) smax[wave][lg * 4 + r] = mx[r];
  }
  __syncthreads();
  float fm[4], den[4] = {0, 0, 0, 0};
#pragma unroll
  for (int r = 0; r < 4; ++r) {
    int qq = lg * 4 + r;
    fm[r] = fmaxf(fmaxf(smax[0][qq], smax[1][qq]), fmaxf(smax[2][qq], smax[3][qq]));
  }
#pragma unroll
  for (int j = 0; j < 5; ++j) {
    if (j < nst) {
#pragma unroll
      for (int r = 0; r < 4; ++r) {
        float pe = __expf(sc[j][r] - fm[r]);
        sc[j][r] = pe;
        den[r] += pe;
      }
    }
  }
#pragma unroll
  for (int r = 0; r < 4; ++r) {
    den[r] += __shfl_xor(den[r], 1, 64);
    den[r] += __shfl_xor(den[r], 2, 64);
    den[r] += __shfl_xor(den[r], 4, 64);
    den[r] += __shfl_xor(den[r], 8, 64);
  }
  if (lc == 0) {
#pragma unroll
    for (int r = 0; r < 4; ++r) sden[wave][lg * 4 + r] = den[r];
  }
  // write P (unnormalized) to LDS; zero tail cols [272..288)
  P[tid >> 4][272 + (tid & 15)] = 0;
#pragma unroll
  for (int j = 0; j < 5; ++j) {
    if (j < nst) {
#pragma unroll
      for (int r = 0; r < 4; ++r) P[lg * 4 + r][st[j] * 16 + lc] = f2bf(sc[j][r]);
    }
  }
  __syncthreads();
  float denf[4];
#pragma unroll
  for (int r = 0; r < 4; ++r) {
    int qq = lg * 4 + r;
    denf[r] = sden[0][qq] + sden[1][qq] + sden[2][qq] + sden[3][qq];
  }
  int d0 = wave * 16;
  float4_t oa = {0, 0, 0, 0};
#pragma unroll
  for (int s9 = 0; s9 < 9; ++s9) {
    short8 pa = *(const short8*)(&P[lc][s9 * 32 + lg * 8]);
    short8 bv = *(const short8*)(vh + (size_t)(d0 + lc) * SPAD + s9 * 32 + lg * 8);
    oa = MFMA(pa, bv, oa);
  }
#pragma unroll
  for (int r = 0; r < 4; ++r) {
    int qg = q0 + lg * 4 + r;
    float val = oa[r] / denf[r];
    ob[(size_t)qg * E_DIM + head * 64 + d0 + lc] = f2bf(val);
  }
}

// ---------------------------------------------------------------------------
// reduce_ln: x[m] += rbias + sum(partials); LayerNorm(x[m]) -> h (bf16)
// grid 257 (one block per token row)
// ---------------------------------------------------------------------------
__global__ __launch_bounds__(256) void reduce_ln_kernel(
    float* __restrict__ x, const float* __restrict__ part, int nparts,
    const float* __restrict__ rbias,
    const float* __restrict__ lns, const float* __restrict__ lnb,
    unsigned short* __restrict__ hout) {
  int m = blockIdx.x, tid = threadIdx.x;
  int c0 = tid * 4;
  float4_t v = *(const float4_t*)(x + (size_t)m * E_DIM + c0);
  if (rbias) v += *(const float4_t*)(rbias + c0);
  for (int s = 0; s < nparts; ++s)
    v += *(const float4_t*)(part + ((size_t)s * MPAD + m) * E_DIM + c0);
  if (nparts > 0) *(float4_t*)(x + (size_t)m * E_DIM + c0) = v;
  float s1 = v[0] + v[1] + v[2] + v[3];
  float s2 = v[0] * v[0] + v[1] * v[1] + v[2] * v[2] + v[3] * v[3];
#pragma unroll
  for (int off = 1; off < 64; off <<= 1) {
    s1 += __shfl_xor(s1, off, 64);
    s2 += __shfl_xor(s2, off, 64);
  }
  __shared__ float red[8];
  int wave = tid >> 6, lane = tid & 63;
  if (lane == 0) { red[wave * 2] = s1; red[wave * 2 + 1] = s2; }
  __syncthreads();
  s1 = red[0] + red[2] + red[4] + red[6];
  s2 = red[1] + red[3] + red[5] + red[7];
  float mean = s1 * (1.f / 1024.f);
  float var = s2 * (1.f / 1024.f) - mean * mean;
  float rstd = rsqrtf(var + 1e-5f);
  float4_t ls = *(const float4_t*)(lns + c0);
  float4_t lb = *(const float4_t*)(lnb + c0);
  ushort4_t hv;
#pragma unroll
  for (int r = 0; r < 4; ++r) hv[r] = f2bf((v[r] - mean) * rstd * ls[r] + lb[r]);
  *(ushort4_t*)(hout + (size_t)m * E_DIM + c0) = hv;
}

// ---------------------------------------------------------------------------
// ROI pool: out[0] = x[0]; out[1+r] = sum_p Mi[r][p] * x[1+p]
// ---------------------------------------------------------------------------
__global__ __launch_bounds__(256) void roi_kernel(const float* __restrict__ x,
                                                  const float* __restrict__ Mi,
                                                  float* __restrict__ out) {
  int b = blockIdx.x, tid = threadIdx.x;
  int c0 = tid * 4;
  if (b == 0) {
    *(float4_t*)(out + c0) = *(const float4_t*)(x + c0);
  } else {
    __shared__ float mi[256];
    mi[tid] = Mi[(b - 1) * 256 + tid];
    __syncthreads();
    float4_t acc = {0, 0, 0, 0};
    for (int p = 0; p < 256; ++p) {
      float4_t xv = *(const float4_t*)(x + (size_t)(1 + p) * E_DIM + c0);
      acc += mi[p] * xv;
    }
    *(float4_t*)(out + (size_t)b * E_DIM + c0) = acc;
  }
}

// ---------------------------------------------------------------------------
extern "C" void kernel_launch(void* const* d_in, const int* in_sizes, int n_in,
                              void* d_out, int out_size, void* d_ws, size_t ws_size,
                              hipStream_t stream) {
  const float* frame   = (const float*)d_in[0];
  const float* bboxes  = (const float*)d_in[1];
  const float* conv_w  = (const float*)d_in[2];
  const float* cls_emb = (const float*)d_in[3];
  const float* ln1_s   = (const float*)d_in[4];
  const float* ln1_b   = (const float*)d_in[5];
  const float* wq = (const float*)d_in[6];
  const float* bq = (const float*)d_in[7];
  const float* wk = (const float*)d_in[8];
  const float* bk = (const float*)d_in[9];
  const float* wv = (const float*)d_in[10];
  const float* bv = (const float*)d_in[11];
  const float* wo = (const float*)d_in[12];
  const float* bo = (const float*)d_in[13];
  const float* ln2_s = (const float*)d_in[14];
  const float* ln2_b = (const float*)d_in[15];
  const float* w1 = (const float*)d_in[16];
  const float* b1 = (const float*)d_in[17];
  const float* w2 = (const float*)d_in[18];
  const float* b2 = (const float*)d_in[19];

  char* base = (char*)d_ws;
  auto carve = [&](size_t bytes) {
    char* r = base;
    base += (bytes + 255) & ~(size_t)255;
    return r;
  };
  float* x            = (float*)carve((size_t)257 * E_DIM * 4);
  unsigned short* h   = (unsigned short*)carve((size_t)MPAD * E_DIM * 2);
  unsigned short* qb  = (unsigned short*)carve((size_t)16 * MPAD * 64 * 2);
  unsigned short* kbf = (unsigned short*)carve((size_t)16 * MPAD * 64 * 2);
  unsigned short* vTb = (unsigned short*)carve((size_t)16 * 64 * SPAD * 2);
  unsigned short* ob  = (unsigned short*)carve((size_t)MPAD * E_DIM * 2);
  unsigned short* mb  = (unsigned short*)carve((size_t)MPAD * FF_DIM * 2);
  float* part         = (float*)carve((size_t)4 * MPAD * E_DIM * 4);
  float* pbv          = (float*)carve(256 * 4);
  float* Mi           = (float*)carve(32 * 256 * 4);
  unsigned short* Pm  = (unsigned short*)carve((size_t)256 * KCP * 2);
  unsigned short* Wp  = (unsigned short*)carve((size_t)1024 * KCP * 2);

  prep_kernel<<<1280, 256, 0, stream>>>(frame, conv_w, Pm, Wp);
  pb_cls_kernel<<<1, 256, 0, stream>>>(bboxes, cls_emb, pbv, Mi, x, h, vTb);
  conv_gemm<<<64, 256, 0, stream>>>(Pm, Wp, x);
  reduce_ln_kernel<<<257, 256, 0, stream>>>(x, nullptr, 0, nullptr, ln1_s, ln1_b, h);

  for (int l = 0; l < LAYERS; ++l) {
    size_t o2  = (size_t)l * E_DIM * E_DIM;
    size_t o1  = (size_t)l * E_DIM;
    size_t of1 = (size_t)l * E_DIM * FF_DIM;
    size_t ofb = (size_t)l * FF_DIM;
    // QKV: N=3072 as 192 n-tiles, no K-split
    gemm_nk<0><<<384, 256, 0, stream>>>(h, E_DIM, wq + o2, wk + o2, wv + o2,
                                        bq + o1, bk + o1, bv + o1,
                                        E_DIM, E_DIM, 192, qb, kbf, vTb, nullptr, nullptr);
    attn_kernel<<<272, 256, 0, stream>>>(qb, kbf, vTb, pbv, ob);
    // O-proj: N=1024, K-split 2 -> partials
    gemm_nk<2><<<256, 256, 0, stream>>>(ob, E_DIM, wo + o2, nullptr, nullptr,
                                        nullptr, nullptr, nullptr,
                                        E_DIM, 512, 64, nullptr, nullptr, nullptr, nullptr, part);
    reduce_ln_kernel<<<257, 256, 0, stream>>>(x, part, 2, bo + o1, ln2_s + o1, ln2_b + o1, h);
    // FF1: N=4096, no K-split; fused bias+quickgelu
    gemm_nk<1><<<512, 256, 0, stream>>>(h, E_DIM, w1 + of1, nullptr, nullptr,
                                        b1 + ofb, nullptr, nullptr,
                                        FF_DIM, E_DIM, 256, nullptr, nullptr, nullptr, mb, nullptr);
    // FF2: N=1024, K=4096, K-split 4 -> partials
    gemm_nk<2><<<512, 256, 0, stream>>>(mb, FF_DIM, w2 + of1, nullptr, nullptr,
                                        nullptr, nullptr, nullptr,
                                        E_DIM, 1024, 64, nullptr, nullptr, nullptr, nullptr, part);
    const float* nls = (l < LAYERS - 1) ? (ln1_s + (size_t)(l + 1) * E_DIM) : ln1_s;
    const float* nlb = (l < LAYERS - 1) ? (ln1_b + (size_t)(l + 1) * E_DIM) : ln1_b;
    reduce_ln_kernel<<<257, 256, 0, stream>>>(x, part, 4, b2 + o1, nls, nlb, h);
  }
  roi_kernel<<<33, 256, 0, stream>>>(x, Mi, (float*)d_out);
}

// Round 2
// 2779.371 us; speedup vs baseline: 1.2585x; 1.2585x over previous
//
#include <hip/hip_runtime.h>
#include <hip/hip_bf16.h>
#include <math.h>

#define E_DIM 1024
#define FF_DIM 4096
#define LAYERS 24
#define MPAD 320      // 20 * 16 token-row padding (rows 257..319 zero / ignored)
#define SPAD 288      // vT / P column padding (9 * 32)
#define KCP 608       // conv K (588) padded to 19*32

typedef __attribute__((ext_vector_type(8))) short short8;
typedef __attribute__((ext_vector_type(8))) __bf16 bf16x8;
typedef __attribute__((ext_vector_type(4))) float float4_t;
typedef __attribute__((ext_vector_type(4))) unsigned short ushort4_t;

union ABu { short8 s; bf16x8 b; };
union BFU { __bf16 b; unsigned short u; };

__device__ __forceinline__ float4_t MFMA(bf16x8 a, bf16x8 b, float4_t c) {
  return __builtin_amdgcn_mfma_f32_16x16x32_bf16(a, b, c, 0, 0, 0);
}
__device__ __forceinline__ float4_t MFMAs(short8 a, short8 b, float4_t c) {
  ABu ua, ub; ua.s = a; ub.s = b;
  return __builtin_amdgcn_mfma_f32_16x16x32_bf16(ua.b, ub.b, c, 0, 0, 0);
}

__device__ __forceinline__ unsigned short f2bf(float f) {
  BFU x; x.b = (__bf16)f; return x.u;
}

// ---------------------------------------------------------------------------
// prep: im2col frame -> Pm[256][608] bf16 ; conv_w -> Wp[1024][608] bf16 ;
// blocks >= 1280 zero the pad regions of h / ob / vT
// ---------------------------------------------------------------------------
__global__ void prep_kernel(const float* __restrict__ frame, const float* __restrict__ conv_w,
                            unsigned short* __restrict__ Pm, unsigned short* __restrict__ Wp,
                            unsigned short* __restrict__ h, unsigned short* __restrict__ ob,
                            unsigned short* __restrict__ vTb) {
  int b = blockIdx.x, tid = threadIdx.x;
  if (b < 256) {
    int pr = b >> 4, pc = b & 15;
    for (int kk = tid; kk < KCP; kk += 256) {
      unsigned short us = 0;
      if (kk < 588) {
        int c = kk / 196, rem = kk % 196;
        int i = rem / 14, j = rem % 14;
        us = f2bf(frame[c * 224 * 224 + (pr * 14 + i) * 224 + (pc * 14 + j)]);
      }
      Pm[b * KCP + kk] = us;
    }
  } else if (b < 1280) {
    int n = b - 256;
    for (int kk = tid; kk < KCP; kk += 256) {
      unsigned short us = (kk < 588) ? f2bf(conv_w[n * 588 + kk]) : (unsigned short)0;
      Wp[n * KCP + kk] = us;
    }
  } else {
    int idx = (b - 1280) * 256 + tid;
    const int NH = (MPAD - 257) * E_DIM;   // 63*1024 = 64512
    const int NO = (MPAD - 272) * E_DIM;   // 48*1024 = 49152
    const int NV = 16 * 64 * (SPAD - 272); // 16384
    if (idx < NH) {
      h[257 * E_DIM + idx] = 0;
    } else if (idx < NH + NO) {
      ob[272 * E_DIM + (idx - NH)] = 0;
    } else if (idx < NH + NO + NV) {
      int i = idx - NH - NO;
      int dr = i >> 4;
      vTb[(size_t)dr * SPAD + 272 + (i & 15)] = 0;
    }
  }
}

// ---------------------------------------------------------------------------
// pb_cls: overlap matrix Mi[32][256], pb[256], x row 0 = cls_emb
// ---------------------------------------------------------------------------
__global__ void pb_cls_kernel(const float* __restrict__ bboxes, const float* __restrict__ cls_emb,
                              float* __restrict__ pb, float* __restrict__ Mi, float* __restrict__ x) {
  __shared__ float sb[128];
  __shared__ float red[256];
  int tid = threadIdx.x;
  if (tid < 128) sb[tid] = bboxes[tid];
  __syncthreads();
  int p = tid;
  float px1 = (float)((p & 15) * 14), py1 = (float)((p >> 4) * 14);
  float px2 = px1 + 14.f, py2 = py1 + 14.f;
  float s = 0.f;
  for (int r = 0; r < 32; ++r) {
    float bx1 = sb[r * 4 + 0], by1 = sb[r * 4 + 1], bx2 = sb[r * 4 + 2], by2 = sb[r * 4 + 3];
    float iw = fmaxf(fminf(bx2, px2) - fmaxf(bx1, px1), 0.f);
    float ih = fmaxf(fminf(by2, py2) - fmaxf(by1, py1), 0.f);
    float ov = iw * ih * (1.f / 196.f);
    Mi[r * 256 + p] = ov;
    s += ov;
  }
  red[tid] = s;
  __syncthreads();
  for (int off = 128; off > 0; off >>= 1) {
    if (tid < off) red[tid] = fmaxf(red[tid], red[tid + off]);
    __syncthreads();
  }
  pb[p] = s / (red[0] + 1e-6f);
  for (int j = 0; j < 4; ++j) x[tid * 4 + j] = cls_emb[tid * 4 + j];
}

// ---------------------------------------------------------------------------
// conv GEMM: x[1+m][n] = relu(Pm[m][:] . Wp[n][:]) ; grid 64 (n-tiles of 16)
// ---------------------------------------------------------------------------
__global__ __launch_bounds__(256) void conv_gemm(const unsigned short* __restrict__ Pm,
                                                 const unsigned short* __restrict__ Wp,
                                                 float* __restrict__ x) {
  int n0 = blockIdx.x * 16;
  int tid = threadIdx.x, wave = tid >> 6, lane = tid & 63;
  int lg = lane >> 4, lc = lane & 15;
  float4_t acc[4] = {{0,0,0,0},{0,0,0,0},{0,0,0,0},{0,0,0,0}};
  const unsigned short* bp = Wp + (size_t)(n0 + lc) * KCP + lg * 8;
  const unsigned short* apt[4];
#pragma unroll
  for (int t = 0; t < 4; ++t) apt[t] = Pm + (size_t)((wave + t * 4) * 16 + lc) * KCP + lg * 8;
  for (int s = 0; s < 19; ++s) {
    short8 bf = *(const short8*)bp; bp += 32;
#pragma unroll
    for (int t = 0; t < 4; ++t) {
      short8 af = *(const short8*)apt[t]; apt[t] += 32;
      acc[t] = MFMAs(af, bf, acc[t]);
    }
  }
#pragma unroll
  for (int t = 0; t < 4; ++t) {
    int mbase = (wave + t * 4) * 16 + lg * 4;
#pragma unroll
    for (int r = 0; r < 4; ++r) {
      float v = fmaxf(acc[t][r], 0.f);
      x[(size_t)(1 + mbase + r) * E_DIM + n0 + lc] = v;
    }
  }
}

// ---------------------------------------------------------------------------
// Swapped-operand GEMM: C[m][n] = A[m][:] (bf16) . W[:][n] (fp32->bf16)
// Block: 16 N-cols x ALL M (20 tiles) x K-chunk. Wave w owns tiles {w+4j}.
// Branch-free K-loop: 8 weight dwords + 5 A short8 + 5 MFMA per step.
// EPI 0: q/k/vT scatter (+bias)  EPI 1: quickgelu -> m_buf (+bias)  EPI 2: fp32 partial
// ---------------------------------------------------------------------------
template <int NTOT, int EPI>
__global__ __launch_bounds__(256) void gemm_nk(
    const unsigned short* __restrict__ A, int lda,
    const float* __restrict__ Wa, const float* __restrict__ Wb, const float* __restrict__ Wc,
    const float* __restrict__ ba, const float* __restrict__ bb, const float* __restrict__ bc,
    int NT, int nsteps,
    unsigned short* __restrict__ oq, unsigned short* __restrict__ okk,
    unsigned short* __restrict__ ovT, unsigned short* __restrict__ om,
    float* __restrict__ opart) {
  int b = blockIdx.x;
  int nt = b % NT, ks = b / NT;

  int tid = threadIdx.x, wave = tid >> 6, lane = tid & 63;
  int lg = lane >> 4, lc = lane & 15;

  const float* W; const float* bias; int ncol;
  if (EPI == 0) {
    int sel = nt >> 6; ncol = (nt & 63) << 4;
    W = (sel == 0) ? Wa : ((sel == 1) ? Wb : Wc);
    bias = (sel == 0) ? ba : ((sel == 1) ? bb : bc);
  } else {
    ncol = nt << 4; W = Wa; bias = ba;
  }

  int kb0 = ks * (nsteps << 5);
  const float* wp = W + (size_t)(kb0 + lg * 8) * NTOT + ncol + lc;
  const unsigned short* ap[5];
#pragma unroll
  for (int j = 0; j < 5; ++j)
    ap[j] = A + (size_t)((wave + 4 * j) * 16 + lc) * lda + kb0 + lg * 8;

  float4_t acc[5] = {{0,0,0,0},{0,0,0,0},{0,0,0,0},{0,0,0,0},{0,0,0,0}};

#pragma unroll 2
  for (int s = 0; s < nsteps; ++s) {
    float wv[8];
#pragma unroll
    for (int i = 0; i < 8; ++i) wv[i] = wp[(size_t)i * NTOT];
    wp += (size_t)32 * NTOT;
    bf16x8 wf;
#pragma unroll
    for (int i = 0; i < 8; ++i) wf[i] = (__bf16)wv[i];
#pragma unroll
    for (int j = 0; j < 5; ++j) {
      ABu a; a.s = *(const short8*)ap[j]; ap[j] += 32;
      acc[j] = MFMA(wf, a.b, acc[j]);
    }
  }

  float4_t bvv = {0,0,0,0};
  if (bias) bvv = *(const float4_t*)(bias + ncol + lg * 4);

  if (EPI == 0) {
    int sel = nt >> 6;
    int head = ncol >> 6;
    int dbase = (ncol & 63) + lg * 4;
#pragma unroll
    for (int j = 0; j < 5; ++j) {
      int tile = wave + 4 * j;
      int m = tile * 16 + lc;
      if (sel < 2) {
        unsigned short* dst = (sel == 0 ? oq : okk) + ((size_t)(head * MPAD + m)) * 64 + dbase;
        ushort4_t hv;
#pragma unroll
        for (int r = 0; r < 4; ++r) hv[r] = f2bf(acc[j][r] + bvv[r]);
        *(ushort4_t*)dst = hv;
      } else if (tile < 17) {   // vT columns only exist for m < 272
#pragma unroll
        for (int r = 0; r < 4; ++r)
          ovT[(size_t)(head * 64 + dbase + r) * SPAD + m] = f2bf(acc[j][r] + bvv[r]);
      }
    }
  } else if (EPI == 1) {
#pragma unroll
    for (int j = 0; j < 5; ++j) {
      int m = (wave + 4 * j) * 16 + lc;
      ushort4_t hv;
#pragma unroll
      for (int r = 0; r < 4; ++r) {
        float v = acc[j][r] + bvv[r];
        v = v / (1.f + __expf(-1.702f * v));   // quick_gelu
        hv[r] = f2bf(v);
      }
      *(ushort4_t*)(om + (size_t)m * FF_DIM + ncol + lg * 4) = hv;
    }
  } else {
#pragma unroll
    for (int j = 0; j < 5; ++j) {
      int m = (wave + 4 * j) * 16 + lc;
      *(float4_t*)(opart + ((size_t)ks * MPAD + m) * E_DIM + ncol + lg * 4) = acc[j];
    }
  }
}

// ---------------------------------------------------------------------------
// Attention: grid = 16 heads * 17 q-tiles; full softmax (max/sum via shfl+LDS)
// ---------------------------------------------------------------------------
__global__ __launch_bounds__(256) void attn_kernel(
    const unsigned short* __restrict__ qb, const unsigned short* __restrict__ kb,
    const unsigned short* __restrict__ vT, const float* __restrict__ pb,
    unsigned short* __restrict__ ob) {
  int head = blockIdx.x / 17, qt = blockIdx.x % 17;
  int q0 = qt * 16;
  int tid = threadIdx.x, wave = tid >> 6, lane = tid & 63;
  int lg = lane >> 4, lc = lane & 15;
  const unsigned short* qh = qb + (size_t)head * MPAD * 64;
  const unsigned short* kh = kb + (size_t)head * MPAD * 64;
  const unsigned short* vh = vT + (size_t)head * 64 * SPAD;

  short8 aq0 = *(const short8*)(qh + (size_t)(q0 + lc) * 64 + lg * 8);
  short8 aq1 = *(const short8*)(qh + (size_t)(q0 + lc) * 64 + 32 + lg * 8);

  float4_t sc[5];
  int st[5]; int nst = 0;
#pragma unroll
  for (int j = 0; j < 5; ++j) {
    int t = wave + j * 4;
    st[j] = (t < 17) ? t : 0;
    if (t < 17) nst = j + 1;
    sc[j] = (float4_t){0,0,0,0};
  }
#pragma unroll
  for (int j = 0; j < 5; ++j) {
    if (j < nst) {
      const unsigned short* kp = kh + (size_t)(st[j] * 16 + lc) * 64 + lg * 8;
      short8 b0 = *(const short8*)kp;
      short8 b1 = *(const short8*)(kp + 32);
      sc[j] = MFMAs(aq0, b0, sc[j]);
      sc[j] = MFMAs(aq1, b1, sc[j]);
    }
  }
  float mx[4] = {-1e30f, -1e30f, -1e30f, -1e30f};
#pragma unroll
  for (int j = 0; j < 5; ++j) {
    if (j < nst) {
      int sg = st[j] * 16 + lc;
#pragma unroll
      for (int r = 0; r < 4; ++r) {
        float v = sc[j][r] * 0.125f;
        if (sg >= 257) v = -1e30f;
        else if (q0 + lg * 4 + r == 0 && sg >= 1) v += pb[sg - 1];
        sc[j][r] = v;
        mx[r] = fmaxf(mx[r], v);
      }
    }
  }
#pragma unroll
  for (int r = 0; r < 4; ++r) {
    mx[r] = fmaxf(mx[r], __shfl_xor(mx[r], 1, 64));
    mx[r] = fmaxf(mx[r], __shfl_xor(mx[r], 2, 64));
    mx[r] = fmaxf(mx[r], __shfl_xor(mx[r], 4, 64));
    mx[r] = fmaxf(mx[r], __shfl_xor(mx[r], 8, 64));
  }
  __shared__ float smax[4][16];
  __shared__ float sden[4][16];
  __shared__ __align__(16) unsigned short P[16][SPAD];
  if (lc == 0) {
#pragma unroll
    for (int r = 0; r < 4; ++r) smax[wave][lg * 4 + r] = mx[r];
  }
  __syncthreads();
  float fm[4], den[4] = {0, 0, 0, 0};
#pragma unroll
  for (int r = 0; r < 4; ++r) {
    int qq = lg * 4 + r;
    fm[r] = fmaxf(fmaxf(smax[0][qq], smax[1][qq]), fmaxf(smax[2][qq], smax[3][qq]));
  }
#pragma unroll
  for (int j = 0; j < 5; ++j) {
    if (j < nst) {
#pragma unroll
      for (int r = 0; r < 4; ++r) {
        float pe = __expf(sc[j][r] - fm[r]);
        sc[j][r] = pe;
        den[r] += pe;
      }
    }
  }
#pragma unroll
  for (int r = 0; r < 4; ++r) {
    den[r] += __shfl_xor(den[r], 1, 64);
    den[r] += __shfl_xor(den[r], 2, 64);
    den[r] += __shfl_xor(den[r], 4, 64);
    den[r] += __shfl_xor(den[r], 8, 64);
  }
  if (lc == 0) {
#pragma unroll
    for (int r = 0; r < 4; ++r) sden[wave][lg * 4 + r] = den[r];
  }
  P[tid >> 4][272 + (tid & 15)] = 0;
#pragma unroll
  for (int j = 0; j < 5; ++j) {
    if (j < nst) {
#pragma unroll
      for (int r = 0; r < 4; ++r) P[lg * 4 + r][st[j] * 16 + lc] = f2bf(sc[j][r]);
    }
  }
  __syncthreads();
  float denf[4];
#pragma unroll
  for (int r = 0; r < 4; ++r) {
    int qq = lg * 4 + r;
    denf[r] = sden[0][qq] + sden[1][qq] + sden[2][qq] + sden[3][qq];
  }
  int d0 = wave * 16;
  float4_t oa = {0, 0, 0, 0};
#pragma unroll
  for (int s9 = 0; s9 < 9; ++s9) {
    short8 pa = *(const short8*)(&P[lc][s9 * 32 + lg * 8]);
    short8 bv = *(const short8*)(vh + (size_t)(d0 + lc) * SPAD + s9 * 32 + lg * 8);
    oa = MFMAs(pa, bv, oa);
  }
#pragma unroll
  for (int r = 0; r < 4; ++r) {
    int qg = q0 + lg * 4 + r;
    float val = oa[r] / denf[r];
    ob[(size_t)qg * E_DIM + head * 64 + d0 + lc] = f2bf(val);
  }
}

// ---------------------------------------------------------------------------
// reduce_ln: x[m] += rbias + sum(partials); LayerNorm(x[m]) -> h (bf16)
// grid 257 (one block per token row)
// ---------------------------------------------------------------------------
__global__ __launch_bounds__(256) void reduce_ln_kernel(
    float* __restrict__ x, const float* __restrict__ part, int nparts,
    const float* __restrict__ rbias,
    const float* __restrict__ lns, const float* __restrict__ lnb,
    unsigned short* __restrict__ hout) {
  int m = blockIdx.x, tid = threadIdx.x;
  int c0 = tid * 4;
  float4_t v = *(const float4_t*)(x + (size_t)m * E_DIM + c0);
  if (rbias) v += *(const float4_t*)(rbias + c0);
  for (int s = 0; s < nparts; ++s)
    v += *(const float4_t*)(part + ((size_t)s * MPAD + m) * E_DIM + c0);
  if (nparts > 0) *(float4_t*)(x + (size_t)m * E_DIM + c0) = v;
  float s1 = v[0] + v[1] + v[2] + v[3];
  float s2 = v[0] * v[0] + v[1] * v[1] + v[2] * v[2] + v[3] * v[3];
#pragma unroll
  for (int off = 1; off < 64; off <<= 1) {
    s1 += __shfl_xor(s1, off, 64);
    s2 += __shfl_xor(s2, off, 64);
  }
  __shared__ float red[8];
  int wave = tid >> 6, lane = tid & 63;
  if (lane == 0) { red[wave * 2] = s1; red[wave * 2 + 1] = s2; }
  __syncthreads();
  s1 = red[0] + red[2] + red[4] + red[6];
  s2 = red[1] + red[3] + red[5] + red[7];
  float mean = s1 * (1.f / 1024.f);
  float var = s2 * (1.f / 1024.f) - mean * mean;
  float rstd = rsqrtf(var + 1e-5f);
  float4_t ls = *(const float4_t*)(lns + c0);
  float4_t lb = *(const float4_t*)(lnb + c0);
  ushort4_t hv;
#pragma unroll
  for (int r = 0; r < 4; ++r) hv[r] = f2bf((v[r] - mean) * rstd * ls[r] + lb[r]);
  *(ushort4_t*)(hout + (size_t)m * E_DIM + c0) = hv;
}

// ---------------------------------------------------------------------------
// ROI pool: out[0] = x[0]; out[1+r] = sum_p Mi[r][p] * x[1+p]
// ---------------------------------------------------------------------------
__global__ __launch_bounds__(256) void roi_kernel(const float* __restrict__ x,
                                                  const float* __restrict__ Mi,
                                                  float* __restrict__ out) {
  int b = blockIdx.x, tid = threadIdx.x;
  int c0 = tid * 4;
  if (b == 0) {
    *(float4_t*)(out + c0) = *(const float4_t*)(x + c0);
  } else {
    __shared__ float mi[256];
    mi[tid] = Mi[(b - 1) * 256 + tid];
    __syncthreads();
    float4_t acc = {0, 0, 0, 0};
    for (int p = 0; p < 256; ++p) {
      float4_t xv = *(const float4_t*)(x + (size_t)(1 + p) * E_DIM + c0);
      acc += mi[p] * xv;
    }
    *(float4_t*)(out + (size_t)b * E_DIM + c0) = acc;
  }
}

// ---------------------------------------------------------------------------
extern "C" void kernel_launch(void* const* d_in, const int* in_sizes, int n_in,
                              void* d_out, int out_size, void* d_ws, size_t ws_size,
                              hipStream_t stream) {
  const float* frame   = (const float*)d_in[0];
  const float* bboxes  = (const float*)d_in[1];
  const float* conv_w  = (const float*)d_in[2];
  const float* cls_emb = (const float*)d_in[3];
  const float* ln1_s   = (const float*)d_in[4];
  const float* ln1_b   = (const float*)d_in[5];
  const float* wq = (const float*)d_in[6];
  const float* bq = (const float*)d_in[7];
  const float* wk = (const float*)d_in[8];
  const float* bk = (const float*)d_in[9];
  const float* wv = (const float*)d_in[10];
  const float* bv = (const float*)d_in[11];
  const float* wo = (const float*)d_in[12];
  const float* bo = (const float*)d_in[13];
  const float* ln2_s = (const float*)d_in[14];
  const float* ln2_b = (const float*)d_in[15];
  const float* w1 = (const float*)d_in[16];
  const float* b1 = (const float*)d_in[17];
  const float* w2 = (const float*)d_in[18];
  const float* b2 = (const float*)d_in[19];

  char* base = (char*)d_ws;
  auto carve = [&](size_t bytes) {
    char* r = base;
    base += (bytes + 255) & ~(size_t)255;
    return r;
  };
  float* x            = (float*)carve((size_t)257 * E_DIM * 4);
  unsigned short* h   = (unsigned short*)carve((size_t)MPAD * E_DIM * 2);
  unsigned short* qb  = (unsigned short*)carve((size_t)16 * MPAD * 64 * 2);
  unsigned short* kbf = (unsigned short*)carve((size_t)16 * MPAD * 64 * 2);
  unsigned short* vTb = (unsigned short*)carve((size_t)16 * 64 * SPAD * 2);
  unsigned short* ob  = (unsigned short*)carve((size_t)MPAD * E_DIM * 2);
  unsigned short* mb  = (unsigned short*)carve((size_t)MPAD * FF_DIM * 2);
  float* part         = (float*)carve((size_t)4 * MPAD * E_DIM * 4);
  float* pbv          = (float*)carve(256 * 4);
  float* Mi           = (float*)carve(32 * 256 * 4);
  unsigned short* Pm  = (unsigned short*)carve((size_t)256 * KCP * 2);
  unsigned short* Wp  = (unsigned short*)carve((size_t)1024 * KCP * 2);

  prep_kernel<<<1280 + 512, 256, 0, stream>>>(frame, conv_w, Pm, Wp, h, ob, vTb);
  pb_cls_kernel<<<1, 256, 0, stream>>>(bboxes, cls_emb, pbv, Mi, x);
  conv_gemm<<<64, 256, 0, stream>>>(Pm, Wp, x);
  reduce_ln_kernel<<<257, 256, 0, stream>>>(x, nullptr, 0, nullptr, ln1_s, ln1_b, h);

  for (int l = 0; l < LAYERS; ++l) {
    size_t o2  = (size_t)l * E_DIM * E_DIM;
    size_t o1  = (size_t)l * E_DIM;
    size_t of1 = (size_t)l * E_DIM * FF_DIM;
    size_t ofb = (size_t)l * FF_DIM;
    // QKV: N=3072 as 192 n-tiles (sel by nt>>6), KS1, K=1024 (32 steps)
    gemm_nk<1024, 0><<<192, 256, 0, stream>>>(h, E_DIM, wq + o2, wk + o2, wv + o2,
                                              bq + o1, bk + o1, bv + o1,
                                              192, 32, qb, kbf, vTb, nullptr, nullptr);
    attn_kernel<<<272, 256, 0, stream>>>(qb, kbf, vTb, pbv, ob);
    // O-proj: N=1024 (64 n-tiles), KS4, chunk 256 (8 steps) -> fp32 partials
    gemm_nk<1024, 2><<<256, 256, 0, stream>>>(ob, E_DIM, wo + o2, nullptr, nullptr,
                                              nullptr, nullptr, nullptr,
                                              64, 8, nullptr, nullptr, nullptr, nullptr, part);
    reduce_ln_kernel<<<257, 256, 0, stream>>>(x, part, 4, bo + o1, ln2_s + o1, ln2_b + o1, h);
    // FF1: N=4096 (256 n-tiles), KS1, K=1024 (32 steps); fused bias+quickgelu
    gemm_nk<4096, 1><<<256, 256, 0, stream>>>(h, E_DIM, w1 + of1, nullptr, nullptr,
                                              b1 + ofb, nullptr, nullptr,
                                              256, 32, nullptr, nullptr, nullptr, mb, nullptr);
    // FF2: N=1024 (64 n-tiles), KS4, K=4096 chunk 1024 (32 steps) -> partials
    gemm_nk<1024, 2><<<256, 256, 0, stream>>>(mb, FF_DIM, w2 + of1, nullptr, nullptr,
                                              nullptr, nullptr, nullptr,
                                              64, 32, nullptr, nullptr, nullptr, nullptr, part);
    const float* nls = (l < LAYERS - 1) ? (ln1_s + (size_t)(l + 1) * E_DIM) : ln1_s;
    const float* nlb = (l < LAYERS - 1) ? (ln1_b + (size_t)(l + 1) * E_DIM) : ln1_b;
    reduce_ln_kernel<<<257, 256, 0, stream>>>(x, part, 4, b2 + o1, nls, nlb, h);
  }
  roi_kernel<<<33, 256, 0, stream>>>(x, Mi, (float*)d_out);
}

// Round 3
// 2689.762 us; speedup vs baseline: 1.3004x; 1.0333x over previous
//
#include <hip/hip_runtime.h>
#include <hip/hip_bf16.h>
#include <math.h>

#define E_DIM 1024
#define FF_DIM 4096
#define LAYERS 24
#define MPAD 320      // 20 * 16 token-row padding (rows 257..319 zero / ignored)
#define SPAD 288      // vT / P column padding (9 * 32)
#define KCP 608       // conv K (588) padded to 19*32

typedef __attribute__((ext_vector_type(8))) short short8;
typedef __attribute__((ext_vector_type(8))) __bf16 bf16x8;
typedef __attribute__((ext_vector_type(4))) float float4_t;
typedef __attribute__((ext_vector_type(4))) unsigned short ushort4_t;

union ABu { short8 s; bf16x8 b; };
union BFU { __bf16 b; unsigned short u; };

__device__ __forceinline__ float4_t MFMA(bf16x8 a, bf16x8 b, float4_t c) {
  return __builtin_amdgcn_mfma_f32_16x16x32_bf16(a, b, c, 0, 0, 0);
}
__device__ __forceinline__ float4_t MFMAs(short8 a, short8 b, float4_t c) {
  ABu ua, ub; ua.s = a; ub.s = b;
  return __builtin_amdgcn_mfma_f32_16x16x32_bf16(ua.b, ub.b, c, 0, 0, 0);
}

__device__ __forceinline__ unsigned short f2bf(float f) {
  BFU x; x.b = (__bf16)f; return x.u;
}

// ---------------------------------------------------------------------------
// prep: im2col frame -> Pm[256][608] bf16 ; conv_w -> Wp[1024][608] bf16 ;
// blocks >= 1280 zero the pad regions of h / ob / vT
// ---------------------------------------------------------------------------
__global__ void prep_kernel(const float* __restrict__ frame, const float* __restrict__ conv_w,
                            unsigned short* __restrict__ Pm, unsigned short* __restrict__ Wp,
                            unsigned short* __restrict__ h, unsigned short* __restrict__ ob,
                            unsigned short* __restrict__ vTb) {
  int b = blockIdx.x, tid = threadIdx.x;
  if (b < 256) {
    int pr = b >> 4, pc = b & 15;
    for (int kk = tid; kk < KCP; kk += 256) {
      unsigned short us = 0;
      if (kk < 588) {
        int c = kk / 196, rem = kk % 196;
        int i = rem / 14, j = rem % 14;
        us = f2bf(frame[c * 224 * 224 + (pr * 14 + i) * 224 + (pc * 14 + j)]);
      }
      Pm[b * KCP + kk] = us;
    }
  } else if (b < 1280) {
    int n = b - 256;
    for (int kk = tid; kk < KCP; kk += 256) {
      unsigned short us = (kk < 588) ? f2bf(conv_w[n * 588 + kk]) : (unsigned short)0;
      Wp[n * KCP + kk] = us;
    }
  } else {
    int idx = (b - 1280) * 256 + tid;
    const int NH = (MPAD - 257) * E_DIM;   // 63*1024 = 64512
    const int NO = (MPAD - 272) * E_DIM;   // 48*1024 = 49152
    const int NV = 16 * 64 * (SPAD - 272); // 16384
    if (idx < NH) {
      h[257 * E_DIM + idx] = 0;
    } else if (idx < NH + NO) {
      ob[272 * E_DIM + (idx - NH)] = 0;
    } else if (idx < NH + NO + NV) {
      int i = idx - NH - NO;
      int dr = i >> 4;
      vTb[(size_t)dr * SPAD + 272 + (i & 15)] = 0;
    }
  }
}

// ---------------------------------------------------------------------------
// pb_cls: overlap matrix Mi[32][256], pb[256], x row 0 = cls_emb
// ---------------------------------------------------------------------------
__global__ void pb_cls_kernel(const float* __restrict__ bboxes, const float* __restrict__ cls_emb,
                              float* __restrict__ pb, float* __restrict__ Mi, float* __restrict__ x) {
  __shared__ float sb[128];
  __shared__ float red[256];
  int tid = threadIdx.x;
  if (tid < 128) sb[tid] = bboxes[tid];
  __syncthreads();
  int p = tid;
  float px1 = (float)((p & 15) * 14), py1 = (float)((p >> 4) * 14);
  float px2 = px1 + 14.f, py2 = py1 + 14.f;
  float s = 0.f;
  for (int r = 0; r < 32; ++r) {
    float bx1 = sb[r * 4 + 0], by1 = sb[r * 4 + 1], bx2 = sb[r * 4 + 2], by2 = sb[r * 4 + 3];
    float iw = fmaxf(fminf(bx2, px2) - fmaxf(bx1, px1), 0.f);
    float ih = fmaxf(fminf(by2, py2) - fmaxf(by1, py1), 0.f);
    float ov = iw * ih * (1.f / 196.f);
    Mi[r * 256 + p] = ov;
    s += ov;
  }
  red[tid] = s;
  __syncthreads();
  for (int off = 128; off > 0; off >>= 1) {
    if (tid < off) red[tid] = fmaxf(red[tid], red[tid + off]);
    __syncthreads();
  }
  pb[p] = s / (red[0] + 1e-6f);
  for (int j = 0; j < 4; ++j) x[tid * 4 + j] = cls_emb[tid * 4 + j];
}

// ---------------------------------------------------------------------------
// conv GEMM: x[1+m][n] = relu(Pm[m][:] . Wp[n][:]) ; grid 64 (n-tiles of 16)
// ---------------------------------------------------------------------------
__global__ __launch_bounds__(256) void conv_gemm(const unsigned short* __restrict__ Pm,
                                                 const unsigned short* __restrict__ Wp,
                                                 float* __restrict__ x) {
  int n0 = blockIdx.x * 16;
  int tid = threadIdx.x, wave = tid >> 6, lane = tid & 63;
  int lg = lane >> 4, lc = lane & 15;
  float4_t acc[4] = {{0,0,0,0},{0,0,0,0},{0,0,0,0},{0,0,0,0}};
  const unsigned short* bp = Wp + (size_t)(n0 + lc) * KCP + lg * 8;
  const unsigned short* apt[4];
#pragma unroll
  for (int t = 0; t < 4; ++t) apt[t] = Pm + (size_t)((wave + t * 4) * 16 + lc) * KCP + lg * 8;
  for (int s = 0; s < 19; ++s) {
    short8 bf = *(const short8*)bp; bp += 32;
#pragma unroll
    for (int t = 0; t < 4; ++t) {
      short8 af = *(const short8*)apt[t]; apt[t] += 32;
      acc[t] = MFMAs(af, bf, acc[t]);
    }
  }
#pragma unroll
  for (int t = 0; t < 4; ++t) {
    int mbase = (wave + t * 4) * 16 + lg * 4;
#pragma unroll
    for (int r = 0; r < 4; ++r) {
      float v = fmaxf(acc[t][r], 0.f);
      x[(size_t)(1 + mbase + r) * E_DIM + n0 + lc] = v;
    }
  }
}

// ---------------------------------------------------------------------------
// Swapped-operand GEMM with explicit 2-deep register prefetch pipeline.
// Block: 16 N-cols x ALL M (20 tiles) x K-chunk. Wave w owns tiles {w+4j}.
// 4 named buffer sets, unroll-by-4: while computing step s, steps s+1..s+3
// have their loads issued -> ~6KB+ weight bytes in flight per wave.
// EPI 0: q/k/vT scatter (+bias)  EPI 1: quickgelu -> m_buf (+bias)  EPI 2: fp32 partial
// ---------------------------------------------------------------------------
#define LOADW(buf) { _Pragma("unroll") for (int i = 0; i < 8; ++i) buf[i] = wp[(size_t)i * NTOT]; wp += (size_t)32 * NTOT; }
#define LOADA(buf) { _Pragma("unroll") for (int j = 0; j < 5; ++j) { buf[j] = *(const short8*)ap[j]; ap[j] += 32; } }
#define COMP(wb, ab) { bf16x8 wf; _Pragma("unroll") for (int i = 0; i < 8; ++i) wf[i] = (__bf16)wb[i]; _Pragma("unroll") for (int j = 0; j < 5; ++j) { ABu u; u.s = ab[j]; acc[j] = MFMA(wf, u.b, acc[j]); } }

template <int NTOT, int EPI, int NSTEPS>
__global__ __launch_bounds__(256) void gemm_nk(
    const unsigned short* __restrict__ A, int lda,
    const float* __restrict__ Wa, const float* __restrict__ Wb, const float* __restrict__ Wc,
    const float* __restrict__ ba, const float* __restrict__ bb, const float* __restrict__ bc,
    int NT,
    unsigned short* __restrict__ oq, unsigned short* __restrict__ okk,
    unsigned short* __restrict__ ovT, unsigned short* __restrict__ om,
    float* __restrict__ opart) {
  static_assert(NSTEPS % 4 == 0 && NSTEPS >= 8, "pipeline needs NSTEPS %4==0, >=8");
  int b = blockIdx.x;
  int nt = b % NT, ks = b / NT;

  int tid = threadIdx.x, wave = tid >> 6, lane = tid & 63;
  int lg = lane >> 4, lc = lane & 15;

  const float* W; const float* bias; int ncol;
  if (EPI == 0) {
    int sel = nt >> 6; ncol = (nt & 63) << 4;
    W = (sel == 0) ? Wa : ((sel == 1) ? Wb : Wc);
    bias = (sel == 0) ? ba : ((sel == 1) ? bb : bc);
  } else {
    ncol = nt << 4; W = Wa; bias = ba;
  }

  int kb0 = ks * (NSTEPS << 5);
  const float* wp = W + (size_t)(kb0 + lg * 8) * NTOT + ncol + lc;
  const unsigned short* ap[5];
#pragma unroll
  for (int j = 0; j < 5; ++j)
    ap[j] = A + (size_t)((wave + 4 * j) * 16 + lc) * lda + kb0 + lg * 8;

  float4_t acc[5] = {{0,0,0,0},{0,0,0,0},{0,0,0,0},{0,0,0,0},{0,0,0,0}};

  float wv0[8], wv1[8], wv2[8], wv3[8];
  short8 av0[5], av1[5], av2[5], av3[5];

  LOADW(wv0) LOADA(av0)          // step 0
  LOADW(wv1) LOADA(av1)          // step 1
  for (int s = 0; s < NSTEPS - 4; s += 4) {
    LOADW(wv2) LOADA(av2)        // step s+2
    COMP(wv0, av0)               // step s
    LOADW(wv3) LOADA(av3)        // step s+3
    COMP(wv1, av1)               // step s+1
    LOADW(wv0) LOADA(av0)        // step s+4
    COMP(wv2, av2)               // step s+2
    LOADW(wv1) LOADA(av1)        // step s+5
    COMP(wv3, av3)               // step s+3
  }
  LOADW(wv2) LOADA(av2)          // step NSTEPS-2
  COMP(wv0, av0)                 // step NSTEPS-4
  LOADW(wv3) LOADA(av3)          // step NSTEPS-1
  COMP(wv1, av1)                 // step NSTEPS-3
  COMP(wv2, av2)                 // step NSTEPS-2
  COMP(wv3, av3)                 // step NSTEPS-1

  float4_t bvv = {0,0,0,0};
  if (bias) bvv = *(const float4_t*)(bias + ncol + lg * 4);

  if (EPI == 0) {
    int sel = nt >> 6;
    int head = ncol >> 6;
    int dbase = (ncol & 63) + lg * 4;
#pragma unroll
    for (int j = 0; j < 5; ++j) {
      int tile = wave + 4 * j;
      int m = tile * 16 + lc;
      if (sel < 2) {
        unsigned short* dst = (sel == 0 ? oq : okk) + ((size_t)(head * MPAD + m)) * 64 + dbase;
        ushort4_t hv;
#pragma unroll
        for (int r = 0; r < 4; ++r) hv[r] = f2bf(acc[j][r] + bvv[r]);
        *(ushort4_t*)dst = hv;
      } else if (tile < 17) {   // vT columns only exist for m < 272
#pragma unroll
        for (int r = 0; r < 4; ++r)
          ovT[(size_t)(head * 64 + dbase + r) * SPAD + m] = f2bf(acc[j][r] + bvv[r]);
      }
    }
  } else if (EPI == 1) {
#pragma unroll
    for (int j = 0; j < 5; ++j) {
      int m = (wave + 4 * j) * 16 + lc;
      ushort4_t hv;
#pragma unroll
      for (int r = 0; r < 4; ++r) {
        float v = acc[j][r] + bvv[r];
        v = v / (1.f + __expf(-1.702f * v));   // quick_gelu
        hv[r] = f2bf(v);
      }
      *(ushort4_t*)(om + (size_t)m * FF_DIM + ncol + lg * 4) = hv;
    }
  } else {
#pragma unroll
    for (int j = 0; j < 5; ++j) {
      int m = (wave + 4 * j) * 16 + lc;
      *(float4_t*)(opart + ((size_t)ks * MPAD + m) * E_DIM + ncol + lg * 4) = acc[j];
    }
  }
}

// ---------------------------------------------------------------------------
// Attention: grid = 16 heads * 17 q-tiles; full softmax (max/sum via shfl+LDS)
// ---------------------------------------------------------------------------
__global__ __launch_bounds__(256) void attn_kernel(
    const unsigned short* __restrict__ qb, const unsigned short* __restrict__ kb,
    const unsigned short* __restrict__ vT, const float* __restrict__ pb,
    unsigned short* __restrict__ ob) {
  int head = blockIdx.x / 17, qt = blockIdx.x % 17;
  int q0 = qt * 16;
  int tid = threadIdx.x, wave = tid >> 6, lane = tid & 63;
  int lg = lane >> 4, lc = lane & 15;
  const unsigned short* qh = qb + (size_t)head * MPAD * 64;
  const unsigned short* kh = kb + (size_t)head * MPAD * 64;
  const unsigned short* vh = vT + (size_t)head * 64 * SPAD;

  short8 aq0 = *(const short8*)(qh + (size_t)(q0 + lc) * 64 + lg * 8);
  short8 aq1 = *(const short8*)(qh + (size_t)(q0 + lc) * 64 + 32 + lg * 8);

  float4_t sc[5];
  int st[5]; int nst = 0;
#pragma unroll
  for (int j = 0; j < 5; ++j) {
    int t = wave + j * 4;
    st[j] = (t < 17) ? t : 0;
    if (t < 17) nst = j + 1;
    sc[j] = (float4_t){0,0,0,0};
  }
#pragma unroll
  for (int j = 0; j < 5; ++j) {
    if (j < nst) {
      const unsigned short* kp = kh + (size_t)(st[j] * 16 + lc) * 64 + lg * 8;
      short8 b0 = *(const short8*)kp;
      short8 b1 = *(const short8*)(kp + 32);
      sc[j] = MFMAs(aq0, b0, sc[j]);
      sc[j] = MFMAs(aq1, b1, sc[j]);
    }
  }
  float mx[4] = {-1e30f, -1e30f, -1e30f, -1e30f};
#pragma unroll
  for (int j = 0; j < 5; ++j) {
    if (j < nst) {
      int sg = st[j] * 16 + lc;
#pragma unroll
      for (int r = 0; r < 4; ++r) {
        float v = sc[j][r] * 0.125f;
        if (sg >= 257) v = -1e30f;
        else if (q0 + lg * 4 + r == 0 && sg >= 1) v += pb[sg - 1];
        sc[j][r] = v;
        mx[r] = fmaxf(mx[r], v);
      }
    }
  }
#pragma unroll
  for (int r = 0; r < 4; ++r) {
    mx[r] = fmaxf(mx[r], __shfl_xor(mx[r], 1, 64));
    mx[r] = fmaxf(mx[r], __shfl_xor(mx[r], 2, 64));
    mx[r] = fmaxf(mx[r], __shfl_xor(mx[r], 4, 64));
    mx[r] = fmaxf(mx[r], __shfl_xor(mx[r], 8, 64));
  }
  __shared__ float smax[4][16];
  __shared__ float sden[4][16];
  __shared__ __align__(16) unsigned short P[16][SPAD];
  if (lc == 0) {
#pragma unroll
    for (int r = 0; r < 4; ++r) smax[wave][lg * 4 + r] = mx[r];
  }
  __syncthreads();
  float fm[4], den[4] = {0, 0, 0, 0};
#pragma unroll
  for (int r = 0; r < 4; ++r) {
    int qq = lg * 4 + r;
    fm[r] = fmaxf(fmaxf(smax[0][qq], smax[1][qq]), fmaxf(smax[2][qq], smax[3][qq]));
  }
#pragma unroll
  for (int j = 0; j < 5; ++j) {
    if (j < nst) {
#pragma unroll
      for (int r = 0; r < 4; ++r) {
        float pe = __expf(sc[j][r] - fm[r]);
        sc[j][r] = pe;
        den[r] += pe;
      }
    }
  }
#pragma unroll
  for (int r = 0; r < 4; ++r) {
    den[r] += __shfl_xor(den[r], 1, 64);
    den[r] += __shfl_xor(den[r], 2, 64);
    den[r] += __shfl_xor(den[r], 4, 64);
    den[r] += __shfl_xor(den[r], 8, 64);
  }
  if (lc == 0) {
#pragma unroll
    for (int r = 0; r < 4; ++r) sden[wave][lg * 4 + r] = den[r];
  }
  P[tid >> 4][272 + (tid & 15)] = 0;
#pragma unroll
  for (int j = 0; j < 5; ++j) {
    if (j < nst) {
#pragma unroll
      for (int r = 0; r < 4; ++r) P[lg * 4 + r][st[j] * 16 + lc] = f2bf(sc[j][r]);
    }
  }
  __syncthreads();
  float denf[4];
#pragma unroll
  for (int r = 0; r < 4; ++r) {
    int qq = lg * 4 + r;
    denf[r] = sden[0][qq] + sden[1][qq] + sden[2][qq] + sden[3][qq];
  }
  int d0 = wave * 16;
  float4_t oa = {0, 0, 0, 0};
#pragma unroll
  for (int s9 = 0; s9 < 9; ++s9) {
    short8 pa = *(const short8*)(&P[lc][s9 * 32 + lg * 8]);
    short8 bv = *(const short8*)(vh + (size_t)(d0 + lc) * SPAD + s9 * 32 + lg * 8);
    oa = MFMAs(pa, bv, oa);
  }
#pragma unroll
  for (int r = 0; r < 4; ++r) {
    int qg = q0 + lg * 4 + r;
    float val = oa[r] / denf[r];
    ob[(size_t)qg * E_DIM + head * 64 + d0 + lc] = f2bf(val);
  }
}

// ---------------------------------------------------------------------------
// reduce_ln: x[m] += rbias + sum(partials); LayerNorm(x[m]) -> h (bf16)
// grid 257 (one block per token row)
// ---------------------------------------------------------------------------
__global__ __launch_bounds__(256) void reduce_ln_kernel(
    float* __restrict__ x, const float* __restrict__ part, int nparts,
    const float* __restrict__ rbias,
    const float* __restrict__ lns, const float* __restrict__ lnb,
    unsigned short* __restrict__ hout) {
  int m = blockIdx.x, tid = threadIdx.x;
  int c0 = tid * 4;
  float4_t v = *(const float4_t*)(x + (size_t)m * E_DIM + c0);
  if (rbias) v += *(const float4_t*)(rbias + c0);
  for (int s = 0; s < nparts; ++s)
    v += *(const float4_t*)(part + ((size_t)s * MPAD + m) * E_DIM + c0);
  if (nparts > 0) *(float4_t*)(x + (size_t)m * E_DIM + c0) = v;
  float s1 = v[0] + v[1] + v[2] + v[3];
  float s2 = v[0] * v[0] + v[1] * v[1] + v[2] * v[2] + v[3] * v[3];
#pragma unroll
  for (int off = 1; off < 64; off <<= 1) {
    s1 += __shfl_xor(s1, off, 64);
    s2 += __shfl_xor(s2, off, 64);
  }
  __shared__ float red[8];
  int wave = tid >> 6, lane = tid & 63;
  if (lane == 0) { red[wave * 2] = s1; red[wave * 2 + 1] = s2; }
  __syncthreads();
  s1 = red[0] + red[2] + red[4] + red[6];
  s2 = red[1] + red[3] + red[5] + red[7];
  float mean = s1 * (1.f / 1024.f);
  float var = s2 * (1.f / 1024.f) - mean * mean;
  float rstd = rsqrtf(var + 1e-5f);
  float4_t ls = *(const float4_t*)(lns + c0);
  float4_t lb = *(const float4_t*)(lnb + c0);
  ushort4_t hv;
#pragma unroll
  for (int r = 0; r < 4; ++r) hv[r] = f2bf((v[r] - mean) * rstd * ls[r] + lb[r]);
  *(ushort4_t*)(hout + (size_t)m * E_DIM + c0) = hv;
}

// ---------------------------------------------------------------------------
// ROI pool: out[0] = x[0]; out[1+r] = sum_p Mi[r][p] * x[1+p]
// ---------------------------------------------------------------------------
__global__ __launch_bounds__(256) void roi_kernel(const float* __restrict__ x,
                                                  const float* __restrict__ Mi,
                                                  float* __restrict__ out) {
  int b = blockIdx.x, tid = threadIdx.x;
  int c0 = tid * 4;
  if (b == 0) {
    *(float4_t*)(out + c0) = *(const float4_t*)(x + c0);
  } else {
    __shared__ float mi[256];
    mi[tid] = Mi[(b - 1) * 256 + tid];
    __syncthreads();
    float4_t acc = {0, 0, 0, 0};
    for (int p = 0; p < 256; ++p) {
      float4_t xv = *(const float4_t*)(x + (size_t)(1 + p) * E_DIM + c0);
      acc += mi[p] * xv;
    }
    *(float4_t*)(out + (size_t)b * E_DIM + c0) = acc;
  }
}

// ---------------------------------------------------------------------------
extern "C" void kernel_launch(void* const* d_in, const int* in_sizes, int n_in,
                              void* d_out, int out_size, void* d_ws, size_t ws_size,
                              hipStream_t stream) {
  const float* frame   = (const float*)d_in[0];
  const float* bboxes  = (const float*)d_in[1];
  const float* conv_w  = (const float*)d_in[2];
  const float* cls_emb = (const float*)d_in[3];
  const float* ln1_s   = (const float*)d_in[4];
  const float* ln1_b   = (const float*)d_in[5];
  const float* wq = (const float*)d_in[6];
  const float* bq = (const float*)d_in[7];
  const float* wk = (const float*)d_in[8];
  const float* bk = (const float*)d_in[9];
  const float* wv = (const float*)d_in[10];
  const float* bv = (const float*)d_in[11];
  const float* wo = (const float*)d_in[12];
  const float* bo = (const float*)d_in[13];
  const float* ln2_s = (const float*)d_in[14];
  const float* ln2_b = (const float*)d_in[15];
  const float* w1 = (const float*)d_in[16];
  const float* b1 = (const float*)d_in[17];
  const float* w2 = (const float*)d_in[18];
  const float* b2 = (const float*)d_in[19];

  char* base = (char*)d_ws;
  auto carve = [&](size_t bytes) {
    char* r = base;
    base += (bytes + 255) & ~(size_t)255;
    return r;
  };
  float* x            = (float*)carve((size_t)257 * E_DIM * 4);
  unsigned short* h   = (unsigned short*)carve((size_t)MPAD * E_DIM * 2);
  unsigned short* qb  = (unsigned short*)carve((size_t)16 * MPAD * 64 * 2);
  unsigned short* kbf = (unsigned short*)carve((size_t)16 * MPAD * 64 * 2);
  unsigned short* vTb = (unsigned short*)carve((size_t)16 * 64 * SPAD * 2);
  unsigned short* ob  = (unsigned short*)carve((size_t)MPAD * E_DIM * 2);
  unsigned short* mb  = (unsigned short*)carve((size_t)MPAD * FF_DIM * 2);
  float* part         = (float*)carve((size_t)8 * MPAD * E_DIM * 4);
  float* pbv          = (float*)carve(256 * 4);
  float* Mi           = (float*)carve(32 * 256 * 4);
  unsigned short* Pm  = (unsigned short*)carve((size_t)256 * KCP * 2);
  unsigned short* Wp  = (unsigned short*)carve((size_t)1024 * KCP * 2);

  prep_kernel<<<1280 + 512, 256, 0, stream>>>(frame, conv_w, Pm, Wp, h, ob, vTb);
  pb_cls_kernel<<<1, 256, 0, stream>>>(bboxes, cls_emb, pbv, Mi, x);
  conv_gemm<<<64, 256, 0, stream>>>(Pm, Wp, x);
  reduce_ln_kernel<<<257, 256, 0, stream>>>(x, nullptr, 0, nullptr, ln1_s, ln1_b, h);

  for (int l = 0; l < LAYERS; ++l) {
    size_t o2  = (size_t)l * E_DIM * E_DIM;
    size_t o1  = (size_t)l * E_DIM;
    size_t of1 = (size_t)l * E_DIM * FF_DIM;
    size_t ofb = (size_t)l * FF_DIM;
    // QKV: N=3072 as 192 n-tiles (sel by nt>>6), KS1, K=1024 (32 steps)
    gemm_nk<1024, 0, 32><<<192, 256, 0, stream>>>(h, E_DIM, wq + o2, wk + o2, wv + o2,
                                                  bq + o1, bk + o1, bv + o1,
                                                  192, qb, kbf, vTb, nullptr, nullptr);
    attn_kernel<<<272, 256, 0, stream>>>(qb, kbf, vTb, pbv, ob);
    // O-proj: N=1024 (64 n-tiles), KS4, chunk 256 (8 steps) -> fp32 partials
    gemm_nk<1024, 2, 8><<<256, 256, 0, stream>>>(ob, E_DIM, wo + o2, nullptr, nullptr,
                                                 nullptr, nullptr, nullptr,
                                                 64, nullptr, nullptr, nullptr, nullptr, part);
    reduce_ln_kernel<<<257, 256, 0, stream>>>(x, part, 4, bo + o1, ln2_s + o1, ln2_b + o1, h);
    // FF1: N=4096 (256 n-tiles), KS1, K=1024 (32 steps); fused bias+quickgelu
    gemm_nk<4096, 1, 32><<<256, 256, 0, stream>>>(h, E_DIM, w1 + of1, nullptr, nullptr,
                                                  b1 + ofb, nullptr, nullptr,
                                                  256, nullptr, nullptr, nullptr, mb, nullptr);
    // FF2: N=1024 (64 n-tiles), KS8, K=4096 chunk 512 (16 steps) -> partials
    gemm_nk<1024, 2, 16><<<512, 256, 0, stream>>>(mb, FF_DIM, w2 + of1, nullptr, nullptr,
                                                  nullptr, nullptr, nullptr,
                                                  64, nullptr, nullptr, nullptr, nullptr, part);
    const float* nls = (l < LAYERS - 1) ? (ln1_s + (size_t)(l + 1) * E_DIM) : ln1_s;
    const float* nlb = (l < LAYERS - 1) ? (ln1_b + (size_t)(l + 1) * E_DIM) : ln1_b;
    reduce_ln_kernel<<<257, 256, 0, stream>>>(x, part, 8, b2 + o1, nls, nlb, h);
  }
  roi_kernel<<<33, 256, 0, stream>>>(x, Mi, (float*)d_out);
}